// Round 14
// baseline (455.951 us; speedup 1.0000x reference)
//
#include <hip/hip_runtime.h>
#include <hip/hip_fp16.h>
#include <math.h>

#define TPB 256
#define PMAX 128       // max partitions
#define PSH 10         // partition = dst >> 10 (1024 nodes/partition; n <= 131072)
#define PW  1024       // nodes per partition
#define CHUNK 8192     // edges per block in count/scatter

__device__ __forceinline__ float leaky02(float x) { return x > 0.f ? x : 0.2f * x; }
__device__ __forceinline__ float eluf(float x) { return x > 0.f ? x : (expf(x) - 1.f); }

// ====================== CSR build (radix-style, R11/R13-verified) ======================

__global__ __launch_bounds__(256) void count_kernel(const int* __restrict__ dst, int E, int n,
                                                    int* __restrict__ counts) {
  __shared__ int lcnt[PMAX];
  int Etot = E + n;
  int c0 = blockIdx.x * CHUNK;
  int c1 = min(c0 + CHUNK, Etot);
  for (int j = threadIdx.x; j < PMAX; j += TPB) lcnt[j] = 0;
  __syncthreads();
  for (int idx = c0 + threadIdx.x; idx < c1; idx += TPB) {
    int dd = (idx < E) ? dst[idx] : (idx - E);
    atomicAdd(&lcnt[dd >> PSH], 1);
  }
  __syncthreads();
  for (int j = threadIdx.x; j < PMAX; j += TPB)
    counts[blockIdx.x * PMAX + j] = lcnt[j];
}

__global__ __launch_bounds__(128) void pscan_kernel(const int* __restrict__ counts, int nbC,
                                                    int* __restrict__ pbase,
                                                    int* __restrict__ pcursor, int NP) {
  __shared__ int sums[PMAX];
  int p = threadIdx.x;
  int s = 0;
  for (int b = 0; b < nbC; b++) s += counts[b * PMAX + p];
  sums[p] = (p < NP) ? s : 0;
  __syncthreads();
  if (p == 0) {
    int acc = 0;
    for (int q = 0; q < NP; q++) { pbase[q] = acc; pcursor[q] = acc; acc += sums[q]; }
    pbase[NP] = acc;
  }
}

__global__ __launch_bounds__(256) void scatter_kernel(const int* __restrict__ src,
                                                      const int* __restrict__ dst,
                                                      int E, int n,
                                                      const int* __restrict__ counts,
                                                      int* __restrict__ pcursor,
                                                      unsigned* __restrict__ pstage) {
  __shared__ int lbase[PMAX];
  __shared__ int lcnt[PMAX];
  int Etot = E + n;
  int c0 = blockIdx.x * CHUNK;
  int c1 = min(c0 + CHUNK, Etot);
  for (int j = threadIdx.x; j < PMAX; j += TPB) {
    int c = counts[blockIdx.x * PMAX + j];
    lbase[j] = atomicAdd(&pcursor[j], c);
    lcnt[j] = 0;
  }
  __syncthreads();
  for (int idx = c0 + threadIdx.x; idx < c1; idx += TPB) {
    int ss, dd;
    if (idx < E) { ss = src[idx]; dd = dst[idx]; }
    else         { ss = dd = idx - E; }
    int p = dd >> PSH;
    int pos = lbase[p] + atomicAdd(&lcnt[p], 1);
    pstage[pos] = ((unsigned)ss << PSH) | (unsigned)(dd & (PW - 1));
  }
}

__global__ __launch_bounds__(1024) void build_csr_kernel(const unsigned* __restrict__ pstage,
                                                         const int* __restrict__ pbase,
                                                         int nvtx,
                                                         int* __restrict__ rowptr,
                                                         int* __restrict__ csr_src) {
  __shared__ int lhist[PW];
  __shared__ int lcur[PW];
  int t = threadIdx.x;
  int p = blockIdx.x;
  int base = pbase[p];
  int end = pbase[p + 1];
  int nodebase = p << PSH;
  lhist[t] = 0;
  __syncthreads();
  for (int i = base + t; i < end; i += 1024)
    atomicAdd(&lhist[pstage[i] & (PW - 1)], 1);
  __syncthreads();
  int v = lhist[t];
  lcur[t] = v;
  __syncthreads();
  for (int off = 1; off < 1024; off <<= 1) {
    int a = (t >= off) ? lcur[t - off] : 0;
    __syncthreads();
    lcur[t] += a;
    __syncthreads();
  }
  int acc = base + lcur[t] - v;
  __syncthreads();
  lcur[t] = acc;
  int node = nodebase + t;
  if (node < nvtx) rowptr[node] = acc;
  __syncthreads();
  for (int i = base + t; i < end; i += 1024) {
    unsigned w = pstage[i];
    int pos = atomicAdd(&lcur[w & (PW - 1)], 1);
    csr_src[pos] = (int)(w >> PSH);
  }
  if (p == (int)gridDim.x - 1 && t == 0) rowptr[nvtx] = end;
}

// ====================== layer-1 transform (x[3] -> h1 fp16 + logits) ======================

__global__ void transform1_kernel(const float* __restrict__ x, const float* __restrict__ W,
                                  const float* __restrict__ a_src, const float* __restrict__ a_dst,
                                  __half* __restrict__ h, float* __restrict__ asrc,
                                  float* __restrict__ adst, int n) {
  __shared__ float sW[3 * 32];
  __shared__ float sa[64];
  if (threadIdx.x < 96) sW[threadIdx.x] = W[threadIdx.x];
  if (threadIdx.x < 32) {
    sa[threadIdx.x] = a_src[threadIdx.x];
    sa[32 + threadIdx.x] = a_dst[threadIdx.x];
  }
  __syncthreads();
  int i = blockIdx.x * blockDim.x + threadIdx.x;
  if (i >= n) return;
  float x0 = x[(size_t)i * 3], x1 = x[(size_t)i * 3 + 1], x2 = x[(size_t)i * 3 + 2];
  float hv[32];
#pragma unroll
  for (int j = 0; j < 32; j++) {
    float acc = x0 * sW[j] + x1 * sW[32 + j] + x2 * sW[64 + j];
    hv[j] = acc;
    h[(size_t)i * 32 + j] = __float2half_rn(acc);
  }
#pragma unroll
  for (int hh = 0; hh < 2; hh++) {
    float as = 0.f, ad = 0.f;
#pragma unroll
    for (int c = 0; c < 16; c++) {
      as += hv[hh * 16 + c] * sa[hh * 16 + c];
      ad += hv[hh * 16 + c] * sa[32 + hh * 16 + c];
    }
    asrc[i * 2 + hh] = as;
    adst[i * 2 + hh] = ad;
  }
}

// ====================== fused GAT layer (32ch, H=2) + next-layer transform ======================
// Gather: unshifted softmax + fp16 hfeat (R12/R13-verified). Epilogue: o=elu(agg+b) staged in
// per-wave LDS, split-k matmul vs LDS-cached Wn, write next h (fp16) + next logits.

// Epilogue -> 32 channels (W2: 32x32, H=2 logits)
__global__ __launch_bounds__(256) void gat12_to32(
    const int* __restrict__ rowptr, const int* __restrict__ csr_src,
    const float* __restrict__ asrc, const float* __restrict__ adst,
    const __half* __restrict__ hfeat,   // [n*32] fp16
    const float* __restrict__ bias,     // [32]
    const float* __restrict__ Wn,       // [32*32] next-layer weight
    const float* __restrict__ aSrcN,    // [32]
    const float* __restrict__ aDstN,    // [32]
    __half* __restrict__ hOut,          // [n*32] fp16
    float* __restrict__ asrcO,          // [n*2]
    float* __restrict__ adstO,          // [n*2]
    int n) {
  __shared__ float2 s_h0[4][64];
  __shared__ float2 s_h1[4][64];
  __shared__ float s_out[4][32];
  __shared__ float sW[32 * 32];
  __shared__ float sa[64];
  for (int j = threadIdx.x; j < 1024; j += TPB) sW[j] = Wn[j];
  if (threadIdx.x < 32) {
    sa[threadIdx.x] = aSrcN[threadIdx.x];
    sa[32 + threadIdx.x] = aDstN[threadIdx.x];
  }
  __syncthreads();

  int wid = threadIdx.x >> 6;
  int lane = threadIdx.x & 63;
  int i = (blockIdx.x * blockDim.x + threadIdx.x) >> 6;
  if (i >= n) return;
  int start = rowptr[i];
  int d = rowptr[i + 1] - start;
  float ad0 = adst[i * 2 + 0];
  float ad1 = adst[i * 2 + 1];
  const uint2* hf = (const uint2*)hfeat;
  int g = lane >> 3;
  int q = lane & 7;
  const float2* swv = (q >= 4) ? s_h1[wid] : s_h0[wid];   // hoisted head select
  float4 acc = make_float4(0.f, 0.f, 0.f, 0.f);
  float sl0 = 0.f, sl1 = 0.f;

  if (d <= 64) {
    int sidx = 0;
    float w0 = 0.f, w1 = 0.f;
    if (lane < d) {
      sidx = csr_src[start + lane];
      float2 av = ((const float2*)asrc)[sidx];
      w0 = expf(leaky02(av.x + ad0));
      w1 = expf(leaky02(av.y + ad1));
    }
    sl0 = w0; sl1 = w1;
    s_h0[wid][lane] = make_float2(__int_as_float(sidx), w0);
    s_h1[wid][lane] = make_float2(__int_as_float(sidx), w1);
    for (int jj = g; jj < d; jj += 8) {
      float2 pw = swv[jj];
      int sb = __float_as_int(pw.x);
      float w = pw.y;
      uint2 raw = hf[(size_t)sb * 8 + q];
      float2 f01 = __half22float2(*reinterpret_cast<const __half2*>(&raw.x));
      float2 f23 = __half22float2(*reinterpret_cast<const __half2*>(&raw.y));
      acc.x += w * f01.x; acc.y += w * f01.y; acc.z += w * f23.x; acc.w += w * f23.y;
    }
  } else {
    for (int base = 0; base < d; base += 64) {
      int k = base + lane;
      int sidx = 0;
      float w0 = 0.f, w1 = 0.f;
      if (k < d) {
        sidx = csr_src[start + k];
        float2 av = ((const float2*)asrc)[sidx];
        w0 = expf(leaky02(av.x + ad0));
        w1 = expf(leaky02(av.y + ad1));
        sl0 += w0; sl1 += w1;
      }
      s_h0[wid][lane] = make_float2(__int_as_float(sidx), w0);
      s_h1[wid][lane] = make_float2(__int_as_float(sidx), w1);
      int cnt = min(64, d - base);
      for (int jj = g; jj < cnt; jj += 8) {
        float2 pw = swv[jj];
        int sb = __float_as_int(pw.x);
        float w = pw.y;
        uint2 raw = hf[(size_t)sb * 8 + q];
        float2 f01 = __half22float2(*reinterpret_cast<const __half2*>(&raw.x));
        float2 f23 = __half22float2(*reinterpret_cast<const __half2*>(&raw.y));
        acc.x += w * f01.x; acc.y += w * f01.y; acc.z += w * f23.x; acc.w += w * f23.y;
      }
    }
  }

#pragma unroll
  for (int off = 32; off >= 1; off >>= 1) {
    sl0 += __shfl_xor(sl0, off);
    sl1 += __shfl_xor(sl1, off);
  }
#pragma unroll
  for (int off = 8; off <= 32; off <<= 1) {
    acc.x += __shfl_xor(acc.x, off);
    acc.y += __shfl_xor(acc.y, off);
    acc.z += __shfl_xor(acc.z, off);
    acc.w += __shfl_xor(acc.w, off);
  }
  if (lane < 8) {
    float inv = 1.f / (((lane >= 4) ? sl1 : sl0) + 1e-16f);
    float4 bv = ((const float4*)bias)[lane];
    float4 o;
    o.x = eluf(acc.x * inv + bv.x);
    o.y = eluf(acc.y * inv + bv.y);
    o.z = eluf(acc.z * inv + bv.z);
    o.w = eluf(acc.w * inv + bv.w);
    ((float4*)&s_out[wid][0])[lane] = o;
  }
  // same-wave LDS ordering: split-k matmul o @ Wn
  int j = lane & 31;
  int hk = lane >> 5;   // k-half
  float part = 0.f;
#pragma unroll
  for (int k = 0; k < 16; k++) {
    int kk = hk * 16 + k;
    part += s_out[wid][kk] * sW[kk * 32 + j];
  }
  part += __shfl_xor(part, 32);   // h_next[j] in lanes 0..31 (dup in 32..63)
  // next-layer logits (per-head 16-lane reduce)
  float ts = part * sa[j];
  float td = part * sa[32 + j];
#pragma unroll
  for (int off = 1; off <= 8; off <<= 1) {
    ts += __shfl_xor(ts, off);
    td += __shfl_xor(td, off);
  }
  float ts1 = __shfl(ts, 16), td1 = __shfl(td, 16);
  if (lane == 0) {
    ((float2*)asrcO)[i] = make_float2(ts, ts1);
    ((float2*)adstO)[i] = make_float2(td, td1);
  }
  // pack h_next to fp16 (16 x half2 = 64B contiguous)
  float hi = __shfl_down(part, 1);
  if ((lane & 1) == 0 && lane < 32) {
    ((__half2*)hOut)[(size_t)i * 16 + (lane >> 1)] =
        __halves2half2(__float2half_rn(part), __float2half_rn(hi));
  }
}

// Epilogue -> 16 channels (W3: 32x16, H=1 logits)
__global__ __launch_bounds__(256) void gat12_to16(
    const int* __restrict__ rowptr, const int* __restrict__ csr_src,
    const float* __restrict__ asrc, const float* __restrict__ adst,
    const __half* __restrict__ hfeat,   // [n*32] fp16
    const float* __restrict__ bias,     // [32]
    const float* __restrict__ Wn,       // [32*16]
    const float* __restrict__ aSrcN,    // [16]
    const float* __restrict__ aDstN,    // [16]
    __half* __restrict__ hOut,          // [n*16] fp16
    float* __restrict__ asrcO,          // [n]
    float* __restrict__ adstO,          // [n]
    int n) {
  __shared__ float2 s_h0[4][64];
  __shared__ float2 s_h1[4][64];
  __shared__ float s_out[4][32];
  __shared__ float sW[32 * 16];
  __shared__ float sa[32];
  for (int j = threadIdx.x; j < 512; j += TPB) sW[j] = Wn[j];
  if (threadIdx.x < 16) {
    sa[threadIdx.x] = aSrcN[threadIdx.x];
    sa[16 + threadIdx.x] = aDstN[threadIdx.x];
  }
  __syncthreads();

  int wid = threadIdx.x >> 6;
  int lane = threadIdx.x & 63;
  int i = (blockIdx.x * blockDim.x + threadIdx.x) >> 6;
  if (i >= n) return;
  int start = rowptr[i];
  int d = rowptr[i + 1] - start;
  float ad0 = adst[i * 2 + 0];
  float ad1 = adst[i * 2 + 1];
  const uint2* hf = (const uint2*)hfeat;
  int g = lane >> 3;
  int q = lane & 7;
  const float2* swv = (q >= 4) ? s_h1[wid] : s_h0[wid];
  float4 acc = make_float4(0.f, 0.f, 0.f, 0.f);
  float sl0 = 0.f, sl1 = 0.f;

  if (d <= 64) {
    int sidx = 0;
    float w0 = 0.f, w1 = 0.f;
    if (lane < d) {
      sidx = csr_src[start + lane];
      float2 av = ((const float2*)asrc)[sidx];
      w0 = expf(leaky02(av.x + ad0));
      w1 = expf(leaky02(av.y + ad1));
    }
    sl0 = w0; sl1 = w1;
    s_h0[wid][lane] = make_float2(__int_as_float(sidx), w0);
    s_h1[wid][lane] = make_float2(__int_as_float(sidx), w1);
    for (int jj = g; jj < d; jj += 8) {
      float2 pw = swv[jj];
      int sb = __float_as_int(pw.x);
      float w = pw.y;
      uint2 raw = hf[(size_t)sb * 8 + q];
      float2 f01 = __half22float2(*reinterpret_cast<const __half2*>(&raw.x));
      float2 f23 = __half22float2(*reinterpret_cast<const __half2*>(&raw.y));
      acc.x += w * f01.x; acc.y += w * f01.y; acc.z += w * f23.x; acc.w += w * f23.y;
    }
  } else {
    for (int base = 0; base < d; base += 64) {
      int k = base + lane;
      int sidx = 0;
      float w0 = 0.f, w1 = 0.f;
      if (k < d) {
        sidx = csr_src[start + k];
        float2 av = ((const float2*)asrc)[sidx];
        w0 = expf(leaky02(av.x + ad0));
        w1 = expf(leaky02(av.y + ad1));
        sl0 += w0; sl1 += w1;
      }
      s_h0[wid][lane] = make_float2(__int_as_float(sidx), w0);
      s_h1[wid][lane] = make_float2(__int_as_float(sidx), w1);
      int cnt = min(64, d - base);
      for (int jj = g; jj < cnt; jj += 8) {
        float2 pw = swv[jj];
        int sb = __float_as_int(pw.x);
        float w = pw.y;
        uint2 raw = hf[(size_t)sb * 8 + q];
        float2 f01 = __half22float2(*reinterpret_cast<const __half2*>(&raw.x));
        float2 f23 = __half22float2(*reinterpret_cast<const __half2*>(&raw.y));
        acc.x += w * f01.x; acc.y += w * f01.y; acc.z += w * f23.x; acc.w += w * f23.y;
      }
    }
  }

#pragma unroll
  for (int off = 32; off >= 1; off >>= 1) {
    sl0 += __shfl_xor(sl0, off);
    sl1 += __shfl_xor(sl1, off);
  }
#pragma unroll
  for (int off = 8; off <= 32; off <<= 1) {
    acc.x += __shfl_xor(acc.x, off);
    acc.y += __shfl_xor(acc.y, off);
    acc.z += __shfl_xor(acc.z, off);
    acc.w += __shfl_xor(acc.w, off);
  }
  if (lane < 8) {
    float inv = 1.f / (((lane >= 4) ? sl1 : sl0) + 1e-16f);
    float4 bv = ((const float4*)bias)[lane];
    float4 o;
    o.x = eluf(acc.x * inv + bv.x);
    o.y = eluf(acc.y * inv + bv.y);
    o.z = eluf(acc.z * inv + bv.z);
    o.w = eluf(acc.w * inv + bv.w);
    ((float4*)&s_out[wid][0])[lane] = o;
  }
  // split-k matmul o(32) @ Wn(32x16): c = lane&15, quarter = lane>>4 sums 8 k's
  int c = lane & 15;
  int p4 = lane >> 4;
  float part = 0.f;
#pragma unroll
  for (int k = 0; k < 8; k++) {
    int kk = p4 * 8 + k;
    part += s_out[wid][kk] * sW[kk * 16 + c];
  }
  part += __shfl_xor(part, 16);
  part += __shfl_xor(part, 32);   // h3[c] in lanes 0..15 (dup elsewhere)
  float ts = part * sa[c];
  float td = part * sa[16 + c];
#pragma unroll
  for (int off = 1; off <= 8; off <<= 1) {
    ts += __shfl_xor(ts, off);
    td += __shfl_xor(td, off);
  }
  if (lane == 0) {
    asrcO[i] = ts;
    adstO[i] = td;
  }
  float hi = __shfl_down(part, 1);
  if ((lane & 1) == 0 && lane < 16) {
    ((__half2*)hOut)[(size_t)i * 8 + (lane >> 1)] =
        __halves2half2(__float2half_rn(part), __float2half_rn(hi));
  }
}

// ====================== layer-3 GAT + output head (R13-verified) ======================

__global__ __launch_bounds__(256) void node_gat3(
    const int* __restrict__ rowptr,
    const int* __restrict__ csr_src,
    const float* __restrict__ asrc,   // [n]
    const float* __restrict__ adst,   // [n]
    const __half* __restrict__ hfeat, // [n*16] fp16
    const float* __restrict__ b3,     // [16]
    const float* __restrict__ Wout,   // [16]
    const float* __restrict__ bout,   // [1]
    float* __restrict__ out,          // [n] sigmoid ++ [n*16] embeddings
    int n) {
  __shared__ float2 s_hw[4][64];
  int wid = threadIdx.x >> 6;
  int lane = threadIdx.x & 63;
  int i = (blockIdx.x * blockDim.x + threadIdx.x) >> 6;
  if (i >= n) return;
  int start = rowptr[i];
  int d = rowptr[i + 1] - start;
  float ad0 = adst[i];
  const uint2* hf = (const uint2*)hfeat;
  int g = lane >> 2;
  int q = lane & 3;
  float4 acc = make_float4(0.f, 0.f, 0.f, 0.f);
  float sl = 0.f;

  if (d <= 64) {
    int sidx = 0;
    float w0 = 0.f;
    if (lane < d) {
      sidx = csr_src[start + lane];
      w0 = expf(leaky02(asrc[sidx] + ad0));
    }
    sl = w0;
    s_hw[wid][lane] = make_float2(__int_as_float(sidx), w0);
    for (int jj = g; jj < d; jj += 16) {
      float2 pw = s_hw[wid][jj];
      int sb = __float_as_int(pw.x);
      float w = pw.y;
      uint2 raw = hf[(size_t)sb * 4 + q];
      float2 f01 = __half22float2(*reinterpret_cast<const __half2*>(&raw.x));
      float2 f23 = __half22float2(*reinterpret_cast<const __half2*>(&raw.y));
      acc.x += w * f01.x; acc.y += w * f01.y; acc.z += w * f23.x; acc.w += w * f23.y;
    }
  } else {
    for (int base = 0; base < d; base += 64) {
      int k = base + lane;
      int sidx = 0;
      float w0 = 0.f;
      if (k < d) {
        sidx = csr_src[start + k];
        w0 = expf(leaky02(asrc[sidx] + ad0));
        sl += w0;
      }
      s_hw[wid][lane] = make_float2(__int_as_float(sidx), w0);
      int cnt = min(64, d - base);
      for (int jj = g; jj < cnt; jj += 16) {
        float2 pw = s_hw[wid][jj];
        int sb = __float_as_int(pw.x);
        float w = pw.y;
        uint2 raw = hf[(size_t)sb * 4 + q];
        float2 f01 = __half22float2(*reinterpret_cast<const __half2*>(&raw.x));
        float2 f23 = __half22float2(*reinterpret_cast<const __half2*>(&raw.y));
        acc.x += w * f01.x; acc.y += w * f01.y; acc.z += w * f23.x; acc.w += w * f23.y;
      }
    }
  }

#pragma unroll
  for (int off = 32; off >= 1; off >>= 1) sl += __shfl_xor(sl, off);
#pragma unroll
  for (int off = 4; off <= 32; off <<= 1) {
    acc.x += __shfl_xor(acc.x, off);
    acc.y += __shfl_xor(acc.y, off);
    acc.z += __shfl_xor(acc.z, off);
    acc.w += __shfl_xor(acc.w, off);
  }
  float z = 0.f;
  if (lane < 4) {
    float inv = 1.f / (sl + 1e-16f);
    float4 bv = ((const float4*)b3)[lane];
    float4 wv = ((const float4*)Wout)[lane];
    float4 o;
    o.x = eluf(acc.x * inv + bv.x);
    o.y = eluf(acc.y * inv + bv.y);
    o.z = eluf(acc.z * inv + bv.z);
    o.w = eluf(acc.w * inv + bv.w);
    ((float4*)(out + n))[(size_t)i * 4 + lane] = o;
    z = o.x * wv.x + o.y * wv.y + o.z * wv.z + o.w * wv.w;
  }
  z += __shfl_xor(z, 1);
  z += __shfl_xor(z, 2);
  if (lane == 0) out[i] = 1.f / (1.f + expf(-(z + bout[0])));
}

// ====================== launch ======================

extern "C" void kernel_launch(void* const* d_in, const int* in_sizes, int n_in,
                              void* d_out, int out_size, void* d_ws, size_t ws_size,
                              hipStream_t stream) {
  const float* x    = (const float*)d_in[0];
  const int*   ei   = (const int*)d_in[1];
  const float* W1   = (const float*)d_in[2];
  const float* as1  = (const float*)d_in[3];
  const float* ad1  = (const float*)d_in[4];
  const float* b1   = (const float*)d_in[5];
  const float* W2   = (const float*)d_in[6];
  const float* as2  = (const float*)d_in[7];
  const float* ad2  = (const float*)d_in[8];
  const float* b2   = (const float*)d_in[9];
  const float* W3   = (const float*)d_in[10];
  const float* as3  = (const float*)d_in[11];
  const float* ad3  = (const float*)d_in[12];
  const float* b3   = (const float*)d_in[13];
  const float* Wout = (const float*)d_in[14];
  const float* bout = (const float*)d_in[15];
  float* out = (float*)d_out;

  const int n = in_sizes[0] / 3;
  const int E = in_sizes[1] / 2;
  const int Etot = E + n;
  const int* src = ei;
  const int* dst = ei + E;
  const int NP = ((n - 1) >> PSH) + 1;   // n=100000 -> 98 partitions
  const int nbC = (Etot + CHUNK - 1) / CHUNK;

  float* ws = (float*)d_ws;
  __half* h1 = (__half*)ws;                       // n*32 half (n*16 f)
  __half* h2 = (__half*)(ws + (size_t)n * 16);    // n*32 half (n*16 f)
  __half* h3 = (__half*)(ws + (size_t)n * 32);    // n*16 half (n*8 f)
  float* asrcA = ws + (size_t)n * 40;             // n*2
  float* adstA = asrcA + (size_t)n * 2;           // n*2
  float* asrcB = adstA + (size_t)n * 2;           // n*2
  float* adstB = asrcB + (size_t)n * 2;           // n*2
  float* asrcC = adstB + (size_t)n * 2;           // n
  float* adstC = asrcC + n;                       // n
  int* rowptr  = (int*)(adstC + n);               // n+1
  int* pbase   = rowptr + n + 1;                  // PMAX+1
  int* pcursor = pbase + PMAX + 1;                // PMAX
  int* csr_src = pcursor + PMAX;                  // Etot
  int* counts  = csr_src + Etot;                  // nbC*PMAX
  unsigned* pstage = (unsigned*)ws;               // Etot (aliases h1/h2/h3; dead before transform1)

  const int nbN = (n + TPB - 1) / TPB;
  const int nbW = (n + 3) / 4;

  // ---- CSR build ----
  count_kernel<<<nbC, TPB, 0, stream>>>(dst, E, n, counts);
  pscan_kernel<<<1, PMAX, 0, stream>>>(counts, nbC, pbase, pcursor, NP);
  scatter_kernel<<<nbC, TPB, 0, stream>>>(src, dst, E, n, counts, pcursor, pstage);
  build_csr_kernel<<<NP, 1024, 0, stream>>>(pstage, pbase, n, rowptr, csr_src);

  // ---- layer 1 transform, then fused GAT+transform chain ----
  transform1_kernel<<<nbN, TPB, 0, stream>>>(x, W1, as1, ad1, h1, asrcA, adstA, n);
  gat12_to32<<<nbW, TPB, 0, stream>>>(rowptr, csr_src, asrcA, adstA, h1, b1,
                                      W2, as2, ad2, h2, asrcB, adstB, n);
  gat12_to16<<<nbW, TPB, 0, stream>>>(rowptr, csr_src, asrcB, adstB, h2, b2,
                                      W3, as3, ad3, h3, asrcC, adstC, n);
  node_gat3<<<nbW, TPB, 0, stream>>>(rowptr, csr_src, asrcC, adstC, h3, b3, Wout, bout, out, n);
}

// Round 15
// 438.698 us; speedup vs baseline: 1.0393x; 1.0393x over previous
//
#include <hip/hip_runtime.h>
#include <hip/hip_fp16.h>
#include <math.h>

#define TPB 256
#define PMAX 128       // max partitions
#define PSH 10         // partition = dst >> 10 (1024 nodes/partition; n <= 131072)
#define PW  1024       // nodes per partition
#define CHUNK 8192     // edges per block in count/scatter

__device__ __forceinline__ float leaky02(float x) { return x > 0.f ? x : 0.2f * x; }
__device__ __forceinline__ float eluf(float x) { return x > 0.f ? x : (expf(x) - 1.f); }

// ====================== CSR build + fused layer-1 transform ======================

// blocks [0,nbC): chunked per-partition edge count (persisted for scan+scatter).
// blocks [nbC,..): layer-1 transform x[3] -> h1 fp16 + attention logits (independent work).
__global__ __launch_bounds__(256) void count_t1_kernel(
    const int* __restrict__ dst, int E, int n, int nbC,
    int* __restrict__ counts,
    const float* __restrict__ x, const float* __restrict__ W1,
    const float* __restrict__ as1, const float* __restrict__ ad1,
    __half* __restrict__ h, float* __restrict__ asrc, float* __restrict__ adst) {
  if ((int)blockIdx.x < nbC) {
    __shared__ int lcnt[PMAX];
    int Etot = E + n;
    int c0 = blockIdx.x * CHUNK;
    int c1 = min(c0 + CHUNK, Etot);
    for (int j = threadIdx.x; j < PMAX; j += TPB) lcnt[j] = 0;
    __syncthreads();
    for (int idx = c0 + threadIdx.x; idx < c1; idx += TPB) {
      int dd = (idx < E) ? dst[idx] : (idx - E);
      atomicAdd(&lcnt[dd >> PSH], 1);
    }
    __syncthreads();
    for (int j = threadIdx.x; j < PMAX; j += TPB)
      counts[blockIdx.x * PMAX + j] = lcnt[j];
  } else {
    __shared__ float sW[96];
    __shared__ float sa[64];
    if (threadIdx.x < 96) sW[threadIdx.x] = W1[threadIdx.x];
    if (threadIdx.x < 32) {
      sa[threadIdx.x] = as1[threadIdx.x];
      sa[32 + threadIdx.x] = ad1[threadIdx.x];
    }
    __syncthreads();
    int i = (blockIdx.x - nbC) * blockDim.x + threadIdx.x;
    if (i >= n) return;
    float x0 = x[(size_t)i * 3], x1 = x[(size_t)i * 3 + 1], x2 = x[(size_t)i * 3 + 2];
    float hv[32];
#pragma unroll
    for (int j = 0; j < 32; j++) {
      float acc = x0 * sW[j] + x1 * sW[32 + j] + x2 * sW[64 + j];
      hv[j] = acc;
      h[(size_t)i * 32 + j] = __float2half_rn(acc);
    }
#pragma unroll
    for (int hh = 0; hh < 2; hh++) {
      float as = 0.f, ad = 0.f;
#pragma unroll
      for (int c = 0; c < 16; c++) {
        as += hv[hh * 16 + c] * sa[hh * 16 + c];
        ad += hv[hh * 16 + c] * sa[32 + hh * 16 + c];
      }
      asrc[i * 2 + hh] = as;
      adst[i * 2 + hh] = ad;
    }
  }
}

__global__ __launch_bounds__(128) void pscan_kernel(const int* __restrict__ counts, int nbC,
                                                    int* __restrict__ pbase,
                                                    int* __restrict__ pcursor, int NP) {
  __shared__ int sums[PMAX];
  int p = threadIdx.x;
  int s = 0;
  for (int b = 0; b < nbC; b++) s += counts[b * PMAX + p];
  sums[p] = (p < NP) ? s : 0;
  __syncthreads();
  if (p == 0) {
    int acc = 0;
    for (int q = 0; q < NP; q++) { pbase[q] = acc; pcursor[q] = acc; acc += sums[q]; }
    pbase[NP] = acc;
  }
}

__global__ __launch_bounds__(256) void scatter_kernel(const int* __restrict__ src,
                                                      const int* __restrict__ dst,
                                                      int E, int n,
                                                      const int* __restrict__ counts,
                                                      int* __restrict__ pcursor,
                                                      unsigned* __restrict__ pstage) {
  __shared__ int lbase[PMAX];
  __shared__ int lcnt[PMAX];
  int Etot = E + n;
  int c0 = blockIdx.x * CHUNK;
  int c1 = min(c0 + CHUNK, Etot);
  for (int j = threadIdx.x; j < PMAX; j += TPB) {
    int c = counts[blockIdx.x * PMAX + j];
    lbase[j] = atomicAdd(&pcursor[j], c);
    lcnt[j] = 0;
  }
  __syncthreads();
  for (int idx = c0 + threadIdx.x; idx < c1; idx += TPB) {
    int ss, dd;
    if (idx < E) { ss = src[idx]; dd = dst[idx]; }
    else         { ss = dd = idx - E; }
    int p = dd >> PSH;
    int pos = lbase[p] + atomicAdd(&lcnt[p], 1);
    pstage[pos] = ((unsigned)ss << PSH) | (unsigned)(dd & (PW - 1));
  }
}

__global__ __launch_bounds__(1024) void build_csr_kernel(const unsigned* __restrict__ pstage,
                                                         const int* __restrict__ pbase,
                                                         int nvtx,
                                                         int* __restrict__ rowptr,
                                                         int* __restrict__ csr_src) {
  __shared__ int lhist[PW];
  __shared__ int lcur[PW];
  int t = threadIdx.x;
  int p = blockIdx.x;
  int base = pbase[p];
  int end = pbase[p + 1];
  int nodebase = p << PSH;
  lhist[t] = 0;
  __syncthreads();
  for (int i = base + t; i < end; i += 1024)
    atomicAdd(&lhist[pstage[i] & (PW - 1)], 1);
  __syncthreads();
  int v = lhist[t];
  lcur[t] = v;
  __syncthreads();
  for (int off = 1; off < 1024; off <<= 1) {
    int a = (t >= off) ? lcur[t - off] : 0;
    __syncthreads();
    lcur[t] += a;
    __syncthreads();
  }
  int acc = base + lcur[t] - v;
  __syncthreads();
  lcur[t] = acc;
  int node = nodebase + t;
  if (node < nvtx) rowptr[node] = acc;
  __syncthreads();
  for (int i = base + t; i < end; i += 1024) {
    unsigned w = pstage[i];
    int pos = atomicAdd(&lcur[w & (PW - 1)], 1);
    csr_src[pos] = (int)(w >> PSH);
  }
  if (p == (int)gridDim.x - 1 && t == 0) rowptr[nvtx] = end;
}

// ====================== node transform (h = x@W fp16, attn logits fp32) ======================

template<int IN, int OUT, int H>
__global__ void transform_kernel(const float* __restrict__ x, const float* __restrict__ W,
                                 const float* __restrict__ a_src, const float* __restrict__ a_dst,
                                 __half* __restrict__ h, float* __restrict__ asrc,
                                 float* __restrict__ adst, int n) {
  __shared__ float sW[IN * OUT];
  __shared__ float sa[2 * OUT];
  for (int i = threadIdx.x; i < IN * OUT; i += blockDim.x) sW[i] = W[i];
  if (threadIdx.x < OUT) {
    sa[threadIdx.x] = a_src[threadIdx.x];
    sa[OUT + threadIdx.x] = a_dst[threadIdx.x];
  }
  __syncthreads();
  int i = blockIdx.x * blockDim.x + threadIdx.x;
  if (i >= n) return;
  float xv[IN];
#pragma unroll
  for (int k = 0; k < IN; k++) xv[k] = x[(size_t)i * IN + k];
  float hv[OUT];
#pragma unroll
  for (int j = 0; j < OUT; j++) {
    float acc = 0.f;
#pragma unroll
    for (int k = 0; k < IN; k++) acc += xv[k] * sW[k * OUT + j];
    hv[j] = acc;
    h[(size_t)i * OUT + j] = __float2half_rn(acc);
  }
#pragma unroll
  for (int hh = 0; hh < H; hh++) {
    float as = 0.f, ad = 0.f;
#pragma unroll
    for (int c = 0; c < 16; c++) {
      as += hv[hh * 16 + c] * sa[hh * 16 + c];
      ad += hv[hh * 16 + c] * sa[OUT + hh * 16 + c];
    }
    asrc[i * H + hh] = as;
    adst[i * H + hh] = ad;
  }
}

// ====================== per-node GAT aggregation (1 wave / dst node) ======================
// Unshifted softmax (R12-verified), fp16 hfeat (R13-verified). Fast path (d<=64, ~all nodes)
// gather loop fully unrolled with predication -> up to 8 independent gathers in flight.

__global__ __launch_bounds__(256) void node_gat12(
    const int* __restrict__ rowptr,
    const int* __restrict__ csr_src,
    const float* __restrict__ asrc,   // [n*2]
    const float* __restrict__ adst,   // [n*2]
    const __half* __restrict__ hfeat, // [n*32] fp16
    const float* __restrict__ bias,   // [32]
    float* __restrict__ outb,         // [n*32] fp32
    int n) {
  __shared__ float2 s_h0[4][64];   // (bitcast sidx, w0)
  __shared__ float2 s_h1[4][64];   // (bitcast sidx, w1)
  int wid = threadIdx.x >> 6;
  int lane = threadIdx.x & 63;
  int i = (blockIdx.x * blockDim.x + threadIdx.x) >> 6;
  if (i >= n) return;
  int start = rowptr[i];
  int d = rowptr[i + 1] - start;
  float ad0 = adst[i * 2 + 0];
  float ad1 = adst[i * 2 + 1];
  const uint2* hf = (const uint2*)hfeat;
  int g = lane >> 3;   // edge group 0..7
  int q = lane & 7;    // slot (q<4: head0 ch, q>=4: head1 ch)
  const float2* swv = (q >= 4) ? s_h1[wid] : s_h0[wid];   // hoisted head select
  float4 acc = make_float4(0.f, 0.f, 0.f, 0.f);
  float sl0 = 0.f, sl1 = 0.f;

  if (d <= 64) {
    int sidx = 0;
    float w0 = 0.f, w1 = 0.f;
    if (lane < d) {
      sidx = csr_src[start + lane];
      float2 av = ((const float2*)asrc)[sidx];
      w0 = expf(leaky02(av.x + ad0));
      w1 = expf(leaky02(av.y + ad1));
    }
    sl0 = w0; sl1 = w1;
    s_h0[wid][lane] = make_float2(__int_as_float(sidx), w0);
    s_h1[wid][lane] = make_float2(__int_as_float(sidx), w1);
    // same-wave LDS write->read ordering (R4-verified); unrolled for load ILP
#pragma unroll
    for (int it = 0; it < 8; it++) {
      int jj = g + it * 8;
      if (jj < d) {
        float2 pw = swv[jj];
        int sb = __float_as_int(pw.x);
        float w = pw.y;
        uint2 raw = hf[(size_t)sb * 8 + q];
        float2 f01 = __half22float2(*reinterpret_cast<const __half2*>(&raw.x));
        float2 f23 = __half22float2(*reinterpret_cast<const __half2*>(&raw.y));
        acc.x += w * f01.x; acc.y += w * f01.y; acc.z += w * f23.x; acc.w += w * f23.y;
      }
    }
  } else {
    for (int base = 0; base < d; base += 64) {
      int k = base + lane;
      int sidx = 0;
      float w0 = 0.f, w1 = 0.f;
      if (k < d) {
        sidx = csr_src[start + k];
        float2 av = ((const float2*)asrc)[sidx];
        w0 = expf(leaky02(av.x + ad0));
        w1 = expf(leaky02(av.y + ad1));
        sl0 += w0; sl1 += w1;
      }
      s_h0[wid][lane] = make_float2(__int_as_float(sidx), w0);
      s_h1[wid][lane] = make_float2(__int_as_float(sidx), w1);
      int cnt = min(64, d - base);
      for (int jj = g; jj < cnt; jj += 8) {
        float2 pw = swv[jj];
        int sb = __float_as_int(pw.x);
        float w = pw.y;
        uint2 raw = hf[(size_t)sb * 8 + q];
        float2 f01 = __half22float2(*reinterpret_cast<const __half2*>(&raw.x));
        float2 f23 = __half22float2(*reinterpret_cast<const __half2*>(&raw.y));
        acc.x += w * f01.x; acc.y += w * f01.y; acc.z += w * f23.x; acc.w += w * f23.y;
      }
    }
  }

#pragma unroll
  for (int off = 32; off >= 1; off >>= 1) {
    sl0 += __shfl_xor(sl0, off);
    sl1 += __shfl_xor(sl1, off);
  }
#pragma unroll
  for (int off = 8; off <= 32; off <<= 1) {
    acc.x += __shfl_xor(acc.x, off);
    acc.y += __shfl_xor(acc.y, off);
    acc.z += __shfl_xor(acc.z, off);
    acc.w += __shfl_xor(acc.w, off);
  }
  if (lane < 8) {
    float inv = 1.f / (((lane >= 4) ? sl1 : sl0) + 1e-16f);
    float4 bv = ((const float4*)bias)[lane];
    float4 o;
    o.x = eluf(acc.x * inv + bv.x);
    o.y = eluf(acc.y * inv + bv.y);
    o.z = eluf(acc.z * inv + bv.z);
    o.w = eluf(acc.w * inv + bv.w);
    ((float4*)outb)[(size_t)i * 8 + lane] = o;
  }
}

__global__ __launch_bounds__(256) void node_gat3(
    const int* __restrict__ rowptr,
    const int* __restrict__ csr_src,
    const float* __restrict__ asrc,   // [n]
    const float* __restrict__ adst,   // [n]
    const __half* __restrict__ hfeat, // [n*16] fp16
    const float* __restrict__ b3,     // [16]
    const float* __restrict__ Wout,   // [16]
    const float* __restrict__ bout,   // [1]
    float* __restrict__ out,          // [n] sigmoid ++ [n*16] embeddings
    int n) {
  __shared__ float2 s_hw[4][64];
  int wid = threadIdx.x >> 6;
  int lane = threadIdx.x & 63;
  int i = (blockIdx.x * blockDim.x + threadIdx.x) >> 6;
  if (i >= n) return;
  int start = rowptr[i];
  int d = rowptr[i + 1] - start;
  float ad0 = adst[i];
  const uint2* hf = (const uint2*)hfeat;
  int g = lane >> 2;   // edge group 0..15
  int q = lane & 3;    // slot
  float4 acc = make_float4(0.f, 0.f, 0.f, 0.f);
  float sl = 0.f;

  if (d <= 64) {
    int sidx = 0;
    float w0 = 0.f;
    if (lane < d) {
      sidx = csr_src[start + lane];
      w0 = expf(leaky02(asrc[sidx] + ad0));
    }
    sl = w0;
    s_hw[wid][lane] = make_float2(__int_as_float(sidx), w0);
#pragma unroll
    for (int it = 0; it < 4; it++) {
      int jj = g + it * 16;
      if (jj < d) {
        float2 pw = s_hw[wid][jj];
        int sb = __float_as_int(pw.x);
        float w = pw.y;
        uint2 raw = hf[(size_t)sb * 4 + q];
        float2 f01 = __half22float2(*reinterpret_cast<const __half2*>(&raw.x));
        float2 f23 = __half22float2(*reinterpret_cast<const __half2*>(&raw.y));
        acc.x += w * f01.x; acc.y += w * f01.y; acc.z += w * f23.x; acc.w += w * f23.y;
      }
    }
  } else {
    for (int base = 0; base < d; base += 64) {
      int k = base + lane;
      int sidx = 0;
      float w0 = 0.f;
      if (k < d) {
        sidx = csr_src[start + k];
        w0 = expf(leaky02(asrc[sidx] + ad0));
        sl += w0;
      }
      s_hw[wid][lane] = make_float2(__int_as_float(sidx), w0);
      int cnt = min(64, d - base);
      for (int jj = g; jj < cnt; jj += 16) {
        float2 pw = s_hw[wid][jj];
        int sb = __float_as_int(pw.x);
        float w = pw.y;
        uint2 raw = hf[(size_t)sb * 4 + q];
        float2 f01 = __half22float2(*reinterpret_cast<const __half2*>(&raw.x));
        float2 f23 = __half22float2(*reinterpret_cast<const __half2*>(&raw.y));
        acc.x += w * f01.x; acc.y += w * f01.y; acc.z += w * f23.x; acc.w += w * f23.y;
      }
    }
  }

#pragma unroll
  for (int off = 32; off >= 1; off >>= 1) sl += __shfl_xor(sl, off);
#pragma unroll
  for (int off = 4; off <= 32; off <<= 1) {
    acc.x += __shfl_xor(acc.x, off);
    acc.y += __shfl_xor(acc.y, off);
    acc.z += __shfl_xor(acc.z, off);
    acc.w += __shfl_xor(acc.w, off);
  }
  float z = 0.f;
  if (lane < 4) {
    float inv = 1.f / (sl + 1e-16f);
    float4 bv = ((const float4*)b3)[lane];
    float4 wv = ((const float4*)Wout)[lane];
    float4 o;
    o.x = eluf(acc.x * inv + bv.x);
    o.y = eluf(acc.y * inv + bv.y);
    o.z = eluf(acc.z * inv + bv.z);
    o.w = eluf(acc.w * inv + bv.w);
    ((float4*)(out + n))[(size_t)i * 4 + lane] = o;
    z = o.x * wv.x + o.y * wv.y + o.z * wv.z + o.w * wv.w;
  }
  z += __shfl_xor(z, 1);
  z += __shfl_xor(z, 2);
  if (lane == 0) out[i] = 1.f / (1.f + expf(-(z + bout[0])));
}

// ====================== launch ======================

extern "C" void kernel_launch(void* const* d_in, const int* in_sizes, int n_in,
                              void* d_out, int out_size, void* d_ws, size_t ws_size,
                              hipStream_t stream) {
  const float* x    = (const float*)d_in[0];
  const int*   ei   = (const int*)d_in[1];
  const float* W1   = (const float*)d_in[2];
  const float* as1  = (const float*)d_in[3];
  const float* ad1  = (const float*)d_in[4];
  const float* b1   = (const float*)d_in[5];
  const float* W2   = (const float*)d_in[6];
  const float* as2  = (const float*)d_in[7];
  const float* ad2  = (const float*)d_in[8];
  const float* b2   = (const float*)d_in[9];
  const float* W3   = (const float*)d_in[10];
  const float* as3  = (const float*)d_in[11];
  const float* ad3  = (const float*)d_in[12];
  const float* b3   = (const float*)d_in[13];
  const float* Wout = (const float*)d_in[14];
  const float* bout = (const float*)d_in[15];
  float* out = (float*)d_out;

  const int n = in_sizes[0] / 3;
  const int E = in_sizes[1] / 2;
  const int Etot = E + n;
  const int* src = ei;
  const int* dst = ei + E;
  const int NP = ((n - 1) >> PSH) + 1;   // n=100000 -> 98 partitions
  const int nbC = (Etot + CHUNK - 1) / CHUNK;
  const int nbN = (n + TPB - 1) / TPB;
  const int nbW = (n + 3) / 4;

  // workspace layout:
  //   hH (fp16 h table, reused all layers)  [0, n*16) floats
  //   bufX (fp32 gat output)                [n*16, n*48)
  //   pstage (transient uint x Etot) ALIASES [n*16, n*16+Etot) -- written before bufX lives,
  //     dead after build_csr. Must NOT alias hH/asrc/adst (t1 is fused into count now).
  float* ws = (float*)d_ws;
  __half* hH  = (__half*)ws;                          // n*32 half
  float* bufX = ws + (size_t)n * 16;                  // n*32 f
  unsigned* pstage = (unsigned*)(ws + (size_t)n * 16);  // Etot uints (aliases bufX)
  size_t post = (size_t)n * 16 + ((size_t)Etot > (size_t)n * 32 ? (size_t)Etot : (size_t)n * 32);
  float* asrc = ws + post;                            // n*2
  float* adst = asrc + (size_t)n * 2;                 // n*2
  int* rowptr  = (int*)(adst + (size_t)n * 2);        // n+1
  int* pbase   = rowptr + n + 1;                      // PMAX+1
  int* pcursor = pbase + PMAX + 1;                    // PMAX
  int* csr_src = pcursor + PMAX;                      // Etot
  int* counts  = csr_src + Etot;                      // nbC*PMAX

  // ---- CSR build (+ fused layer-1 transform) ----
  count_t1_kernel<<<nbC + nbN, TPB, 0, stream>>>(dst, E, n, nbC, counts,
                                                 x, W1, as1, ad1, hH, asrc, adst);
  pscan_kernel<<<1, PMAX, 0, stream>>>(counts, nbC, pbase, pcursor, NP);
  scatter_kernel<<<nbC, TPB, 0, stream>>>(src, dst, E, n, counts, pcursor, pstage);
  build_csr_kernel<<<NP, 1024, 0, stream>>>(pstage, pbase, n, rowptr, csr_src);

  // ---- layer 1 GAT ----
  node_gat12<<<nbW, TPB, 0, stream>>>(rowptr, csr_src, asrc, adst, hH, b1, bufX, n);
  // ---- layer 2 ----
  transform_kernel<32, 32, 2><<<nbN, TPB, 0, stream>>>(bufX, W2, as2, ad2, hH, asrc, adst, n);
  node_gat12<<<nbW, TPB, 0, stream>>>(rowptr, csr_src, asrc, adst, hH, b2, bufX, n);
  // ---- layer 3 ----
  transform_kernel<32, 16, 1><<<nbN, TPB, 0, stream>>>(bufX, W3, as3, ad3, hH, asrc, adst, n);
  node_gat3<<<nbW, TPB, 0, stream>>>(rowptr, csr_src, asrc, adst, hH, b3, Wout, bout, out, n);
}